// Round 1
// baseline (1599.347 us; speedup 1.0000x reference)
//
#include <hip/hip_runtime.h>
#include <hip/hip_bf16.h>
#include <stdint.h>

#define TOKENS 8192
#define DIN    4096
#define DOUT   16384

typedef short s16x8 __attribute__((ext_vector_type(8)));
typedef float f32x4 __attribute__((ext_vector_type(4)));

__device__ __forceinline__ unsigned short f2bf(float f) {
  unsigned int u = __float_as_uint(f);
  u += 0x7fffu + ((u >> 16) & 1u);   // round-to-nearest-even
  return (unsigned short)(u >> 16);
}

// -------- Kernel 1: LayerNorm (no affine) fp32 -> bf16 bits, one block per row
__global__ __launch_bounds__(256) void ln_kernel(const float* __restrict__ x,
                                                 unsigned short* __restrict__ xn) {
  const int row = blockIdx.x;
  const float4* xr = reinterpret_cast<const float4*>(x + (size_t)row * DIN);
  float4 v[4];
  float sum = 0.f, ssq = 0.f;
#pragma unroll
  for (int i = 0; i < 4; ++i) {
    v[i] = xr[threadIdx.x + i * 256];
    sum += v[i].x + v[i].y + v[i].z + v[i].w;
    ssq += v[i].x * v[i].x + v[i].y * v[i].y + v[i].z * v[i].z + v[i].w * v[i].w;
  }
#pragma unroll
  for (int off = 32; off > 0; off >>= 1) {
    sum += __shfl_xor(sum, off, 64);
    ssq += __shfl_xor(ssq, off, 64);
  }
  __shared__ float red[8];
  const int wid = threadIdx.x >> 6;
  if ((threadIdx.x & 63) == 0) { red[wid] = sum; red[wid + 4] = ssq; }
  __syncthreads();
  sum = red[0] + red[1] + red[2] + red[3];
  ssq = red[4] + red[5] + red[6] + red[7];
  const float mean = sum * (1.f / DIN);
  const float var  = ssq * (1.f / DIN) - mean * mean;  // biased, as torch LN
  const float rs   = rsqrtf(var + 1e-5f);
  ushort4* xo = reinterpret_cast<ushort4*>(xn + (size_t)row * DIN);
#pragma unroll
  for (int i = 0; i < 4; ++i) {
    ushort4 o;
    o.x = f2bf((v[i].x - mean) * rs);
    o.y = f2bf((v[i].y - mean) * rs);
    o.z = f2bf((v[i].z - mean) * rs);
    o.w = f2bf((v[i].w - mean) * rs);
    xo[threadIdx.x + i * 256] = o;
  }
}

// -------- Kernel 2: W fp32 -> bf16 bits (vectorized float4 -> ushort4)
__global__ __launch_bounds__(256) void cvt_kernel(const float* __restrict__ W,
                                                  unsigned short* __restrict__ Wb) {
  const size_t i = (size_t)blockIdx.x * 256 + threadIdx.x;
  float4 v = reinterpret_cast<const float4*>(W)[i];
  ushort4 o;
  o.x = f2bf(v.x); o.y = f2bf(v.y); o.z = f2bf(v.z); o.w = f2bf(v.w);
  reinterpret_cast<ushort4*>(Wb)[i] = o;
}

// -------- Kernel 3: C = sigmoid(A @ B^T); A [M,K] bf16, B [N,K] bf16, C [M,N] fp32
// m97 structure: 128x128 tile, BK=32, 4 waves (2x2), 16x16x32 MFMA,
// global_load_lds width=16, 2-barrier K-loop.
__global__ __launch_bounds__(256) void gemm_sig(const unsigned short* __restrict__ A,
                                                const unsigned short* __restrict__ B,
                                                float* __restrict__ C) {
  __shared__ unsigned short As[128 * 32];  // 8 KB, linear (global_load_lds needs contiguous)
  __shared__ unsigned short Bs[128 * 32];  // 8 KB

  // XCD-aware bijective swizzle (nwg = 8192, divisible by 8)
  const int nwg = gridDim.x;
  const int bid = blockIdx.x;
  const int cpx = nwg >> 3;
  const int swz = (bid & 7) * cpx + (bid >> 3);
  const int Mt  = TOKENS / 128;           // 64
  const int bm  = swz % Mt;
  const int bn  = swz / Mt;

  const int tid  = threadIdx.x;
  const int wid  = tid >> 6;
  const int lane = tid & 63;
  const int wr   = wid >> 1, wc = wid & 1;   // wave -> 64x64 output quadrant

  const unsigned short* gA = A + (size_t)bm * 128 * DIN;
  const unsigned short* gB = B + (size_t)bn * 128 * DIN;

  f32x4 acc[4][4] = {};

  const int frow = lane & 15;
  const int fk8  = (lane >> 4) * 8;
  int aoff[4], boff[4];
#pragma unroll
  for (int m = 0; m < 4; ++m) aoff[m] = (wr * 64 + m * 16 + frow) * 32 + fk8;
#pragma unroll
  for (int n = 0; n < 4; ++n) boff[n] = (wc * 64 + n * 16 + frow) * 32 + fk8;

  for (int kt = 0; kt < DIN / 32; ++kt) {
    __syncthreads();  // all waves done reading LDS from previous step
#pragma unroll
    for (int call = 0; call < 2; ++call) {
      // chunk c covers LDS bytes [c*16, c*16+16): row = c>>2, 16B piece (c&3)
      const int c = call * 256 + tid;
      const unsigned short* gpA = gA + (size_t)(c >> 2) * DIN + kt * 32 + (c & 3) * 8;
      const unsigned short* gpB = gB + (size_t)(c >> 2) * DIN + kt * 32 + (c & 3) * 8;
      char* lpA = (char*)As + call * 4096 + wid * 1024;  // wave-uniform base + lane*16
      char* lpB = (char*)Bs + call * 4096 + wid * 1024;
      __builtin_amdgcn_global_load_lds((const __attribute__((address_space(1))) void*)gpA,
                                       (__attribute__((address_space(3))) void*)lpA, 16, 0, 0);
      __builtin_amdgcn_global_load_lds((const __attribute__((address_space(1))) void*)gpB,
                                       (__attribute__((address_space(3))) void*)lpB, 16, 0, 0);
    }
    __syncthreads();  // vmcnt(0) drained before barrier -> tile visible

    s16x8 af[4], bfr[4];
#pragma unroll
    for (int m = 0; m < 4; ++m) af[m]  = *reinterpret_cast<const s16x8*>(As + aoff[m]);
#pragma unroll
    for (int n = 0; n < 4; ++n) bfr[n] = *reinterpret_cast<const s16x8*>(Bs + boff[n]);
#pragma unroll
    for (int m = 0; m < 4; ++m)
#pragma unroll
      for (int n = 0; n < 4; ++n)
        acc[m][n] = __builtin_amdgcn_mfma_f32_16x16x32_bf16(af[m], bfr[n], acc[m][n], 0, 0, 0);
  }

  // Epilogue: C/D layout col = lane&15, row = (lane>>4)*4 + j  (m89/m91 verified)
  const int crow0 = bm * 128 + wr * 64 + (lane >> 4) * 4;
  const int ccol0 = bn * 128 + wc * 64 + (lane & 15);
#pragma unroll
  for (int m = 0; m < 4; ++m)
#pragma unroll
    for (int n = 0; n < 4; ++n)
#pragma unroll
      for (int j = 0; j < 4; ++j) {
        const float v = acc[m][n][j];
        C[(size_t)(crow0 + m * 16 + j) * DOUT + (ccol0 + n * 16)] = 1.f / (1.f + __expf(-v));
      }
}

extern "C" void kernel_launch(void* const* d_in, const int* in_sizes, int n_in,
                              void* d_out, int out_size, void* d_ws, size_t ws_size,
                              hipStream_t stream) {
  const float* x = (const float*)d_in[0];
  const float* W = (const float*)d_in[1];
  float* out = (float*)d_out;

  // workspace: xn bf16 [8192,4096] (64 MiB) | Wb bf16 [16384,4096] (128 MiB)
  unsigned short* xn = (unsigned short*)d_ws;
  unsigned short* Wb = xn + (size_t)TOKENS * DIN;

  ln_kernel<<<TOKENS, 256, 0, stream>>>(x, xn);
  cvt_kernel<<<((size_t)DOUT * DIN) / 1024, 256, 0, stream>>>(W, Wb);
  gemm_sig<<<(TOKENS / 128) * (DOUT / 128), 256, 0, stream>>>(xn, Wb, out);
}